// Round 2
// baseline (2809.494 us; speedup 1.0000x reference)
//
#include <hip/hip_runtime.h>
#include <hip/hip_bf16.h>

// ---------------------------------------------------------------------------
// D-MPNN molecule encoder. fp32 compute, bf16 storage for big intermediates.
// Workspace budget: 268.6 MB (prev 729 MB version aborted -> suspected ws OOB).
//
// Buffers:
//   buf0 [B,256] bf16 : pre-relu `inputs`; overwritten by msg2 in iter 2
//   buf1 [B,256] bf16 : msg1; later reused for atom_hiddens [A,256]
//   amsg [A,256] bf16 : neighbor sums
//   molv [4096,256] f32, hbuf [4096,512] f32
//
// relu is applied ON READ in gathers/diff-loader (idempotent for post-relu
// messages), so pre-relu `inputs` doubles as message 0.
// ---------------------------------------------------------------------------

typedef __hip_bfloat16 bf16;

__device__ __forceinline__ float b2f(bf16 x) { return __bfloat162float(x); }
__device__ __forceinline__ bf16  f2b(float x) { return __float2bfloat16(x); }

#define TM 64
#define TN 64
#define TK 16

// MODE 0: A[row,k] = k<K1 ? Af1[row,k] : Af2[row,k-K1]            (fp32|fp32)
// MODE 1: A[row,k] = amsg[g1[row],k] - relu(msg[g2[row],k])       (bf16, stride K)
// MODE 2: A[row,k] = k<K1 ? Af1[row,k] : b2f(Ab1[row,k-K1])       (fp32|bf16)
// OUT  0: outB[o] = bf16(pre-activation)
// OUT  1: outB[o] = bf16(relu(v))
// OUT  2: outF[o] = relu(v)
template <int MODE, int OUT>
__global__ __launch_bounds__(256) void gemm_k(
    int M, int N, int K, int K1,
    const float* __restrict__ Af1,
    const float* __restrict__ Af2,
    const bf16* __restrict__ Ab1,
    const bf16* __restrict__ Ab2,
    const int* __restrict__ g1,
    const int* __restrict__ g2,
    const float* __restrict__ W,
    const float* __restrict__ bias,
    const bf16* __restrict__ addC,
    bf16* __restrict__ outB,
    float* __restrict__ outF)
{
    __shared__ float As[TK][TM + 4];
    __shared__ float Bs[TK][TN + 4];

    const int bm = blockIdx.x * TM;
    const int bn = blockIdx.y * TN;
    const int t  = threadIdx.x;
    const int tx = t & 15;   // N dir, 4 cols each
    const int ty = t >> 4;   // M dir, 4 rows each

    float acc[4][4] = {};

    for (int k0 = 0; k0 < K; k0 += TK) {
        // stage A tile: TM rows x TK k
        #pragma unroll
        for (int i = 0; i < 4; i++) {
            int idx = t + i * 256;
            int r  = idx >> 4;
            int kk = idx & 15;
            int row = bm + r, k = k0 + kk;
            float v = 0.f;
            if (row < M && k < K) {
                if (MODE == 0) {
                    v = (k < K1) ? Af1[(size_t)row * K1 + k]
                                 : Af2[(size_t)row * (K - K1) + (k - K1)];
                } else if (MODE == 1) {
                    int r1 = g1[row], r2 = g2[row];
                    v = b2f(Ab1[(size_t)r1 * K + k])
                        - fmaxf(b2f(Ab2[(size_t)r2 * K + k]), 0.f);
                } else { // MODE 2
                    v = (k < K1) ? Af1[(size_t)row * K1 + k]
                                 : b2f(Ab1[(size_t)row * (K - K1) + (k - K1)]);
                }
            }
            As[kk][r] = v;
        }
        // stage W tile: TK k x TN n
        #pragma unroll
        for (int i = 0; i < 4; i++) {
            int idx = t + i * 256;
            int nn = idx & 63;
            int kk = idx >> 6;
            int k = k0 + kk, n = bn + nn;
            float v = 0.f;
            if (k < K && n < N) v = W[(size_t)k * N + n];
            Bs[kk][nn] = v;
        }
        __syncthreads();

        #pragma unroll
        for (int kk = 0; kk < TK; kk++) {
            float a[4], b[4];
            #pragma unroll
            for (int i = 0; i < 4; i++) a[i] = As[kk][ty * 4 + i];
            #pragma unroll
            for (int j = 0; j < 4; j++) b[j] = Bs[kk][tx * 4 + j];
            #pragma unroll
            for (int i = 0; i < 4; i++)
                #pragma unroll
                for (int j = 0; j < 4; j++)
                    acc[i][j] += a[i] * b[j];
        }
        __syncthreads();
    }

    #pragma unroll
    for (int i = 0; i < 4; i++) {
        int row = bm + ty * 4 + i;
        if (row >= M) continue;
        #pragma unroll
        for (int j = 0; j < 4; j++) {
            int n = bn + tx * 4 + j;
            if (n >= N) continue;
            float v = acc[i][j];
            if (bias) v += bias[n];
            size_t o = (size_t)row * N + n;
            if (addC) v += b2f(addC[o]);   // same-thread read-before-write when aliased with outB
            if (OUT == 0) outB[o] = f2b(v);
            else if (OUT == 1) outB[o] = f2b(fmaxf(v, 0.f));
            else outF[o] = fmaxf(v, 0.f);
        }
    }
}

// amsg[a,h] = sum_k relu(msg[a2b[a,k], h]) ; one block per atom, 256 thr = H
__global__ __launch_bounds__(256) void gather_sum_kernel(
    const bf16* __restrict__ msg, const int* __restrict__ a2b,
    bf16* __restrict__ amsg, int A)
{
    int a = blockIdx.x;
    if (a >= A) return;
    int h = threadIdx.x;
    const int* nb = a2b + (size_t)a * 6;
    float s = 0.f;
    #pragma unroll
    for (int k = 0; k < 6; k++)
        s += fmaxf(b2f(msg[(size_t)nb[k] * 256 + h]), 0.f);
    amsg[(size_t)a * 256 + h] = f2b(s);
}

// molv[m,h] = mean over the sorted segment atom2mol==m (0 if empty)
__global__ __launch_bounds__(256) void segment_mean_kernel(
    const bf16* __restrict__ ah, const int* __restrict__ atom2mol,
    int A, float* __restrict__ molv)
{
    int m = blockIdx.x;
    int h = threadIdx.x;
    int lo = 0, hi = A;
    while (lo < hi) { int mid = (lo + hi) >> 1; if (atom2mol[mid] < m) lo = mid + 1; else hi = mid; }
    int start = lo;
    hi = A;
    while (lo < hi) { int mid = (lo + hi) >> 1; if (atom2mol[mid] <= m) lo = mid + 1; else hi = mid; }
    int end = lo;
    float s = 0.f;
    for (int a = start; a < end; a++) s += b2f(ah[(size_t)a * 256 + h]);
    float cnt = (float)(end - start);
    molv[(size_t)m * 256 + h] = s / fmaxf(cnt, 1.f);
}

extern "C" void kernel_launch(void* const* d_in, const int* in_sizes, int n_in,
                              void* d_out, int out_size, void* d_ws, size_t ws_size,
                              hipStream_t stream)
{
    const float* f_atoms  = (const float*)d_in[0];
    const float* f_bonds  = (const float*)d_in[1];
    const int*   a2b      = (const int*)d_in[2];
    const int*   b2a      = (const int*)d_in[3];
    const int*   b2revb   = (const int*)d_in[4];
    const int*   atom2mol = (const int*)d_in[5];
    const float* mol_feat = (const float*)d_in[6];
    const float* W_i      = (const float*)d_in[7];
    const float* W_h      = (const float*)d_in[8];
    const float* W_o_w    = (const float*)d_in[9];
    const float* W_o_b    = (const float*)d_in[10];
    const float* W1       = (const float*)d_in[11];
    const float* b1       = (const float*)d_in[12];
    const float* W2       = (const float*)d_in[13];
    const float* b2       = (const float*)d_in[14];

    const int A  = 100000, B = 200000, H = 256;
    const int AF = 133, BF = 147;
    const int NM = 4096, MF = 200, FH = 512, EH = 256;

    char* ws = (char*)d_ws;
    bf16* buf0 = (bf16*)ws;  ws += (size_t)B * H * sizeof(bf16);   // 102.4 MB
    bf16* buf1 = (bf16*)ws;  ws += (size_t)B * H * sizeof(bf16);   // 102.4 MB
    bf16* amsg = (bf16*)ws;  ws += (size_t)A * H * sizeof(bf16);   //  51.2 MB
    float* molv = (float*)ws; ws += (size_t)NM * H * sizeof(float);  // 4 MB
    float* hbuf = (float*)ws; ws += (size_t)NM * FH * sizeof(float); // 8 MB
    // total 268.6 MB

    dim3 blk(256);

    // 1. buf0 = f_bonds @ W_i   (pre-relu "inputs" == pre-relu message 0)
    gemm_k<0, 0><<<dim3((B + TM - 1) / TM, H / TN), blk, 0, stream>>>(
        B, H, BF, BF,
        f_bonds, nullptr, nullptr, nullptr, nullptr, nullptr,
        W_i, nullptr, nullptr, buf0, nullptr);

    // 2a. iter 1: amsg = gather-relu-sum(buf0); buf1 = relu(inputs + diff@W_h)
    //     rev-gather source = buf0 (message 0 via relu-on-read)
    gather_sum_kernel<<<dim3(A), blk, 0, stream>>>(buf0, a2b, amsg, A);
    gemm_k<1, 1><<<dim3((B + TM - 1) / TM, H / TN), blk, 0, stream>>>(
        B, H, H, H,
        nullptr, nullptr, amsg, buf0, b2a, b2revb,
        W_h, nullptr, buf0, buf1, nullptr);

    // 2b. iter 2: amsg = gather-relu-sum(buf1); buf0 = relu(inputs + diff@W_h)
    //     rev-gather source = buf1 (msg1); residual reads buf0[row] (inputs),
    //     written in-place by the same thread after the read.
    gather_sum_kernel<<<dim3(A), blk, 0, stream>>>(buf1, a2b, amsg, A);
    gemm_k<1, 1><<<dim3((B + TM - 1) / TM, H / TN), blk, 0, stream>>>(
        B, H, H, H,
        nullptr, nullptr, amsg, buf1, b2a, b2revb,
        W_h, nullptr, buf0, buf0, nullptr);

    // 3. final neighbor sum from buf0 (msg2, already relu'd; relu idempotent)
    gather_sum_kernel<<<dim3(A), blk, 0, stream>>>(buf0, a2b, amsg, A);

    // 4. atom_hiddens = relu([f_atoms | amsg] @ W_o_w + b) -> reuse buf1
    gemm_k<2, 1><<<dim3((A + TM - 1) / TM, H / TN), blk, 0, stream>>>(
        A, H, AF + H, AF,
        f_atoms, nullptr, amsg, nullptr, nullptr, nullptr,
        W_o_w, W_o_b, nullptr, buf1, nullptr);

    // 5. per-molecule mean
    segment_mean_kernel<<<dim3(NM), blk, 0, stream>>>(buf1, atom2mol, A, molv);

    // 6. hbuf = relu([molv | mol_feat] @ W1 + b1)
    gemm_k<0, 2><<<dim3((NM + TM - 1) / TM, FH / TN), blk, 0, stream>>>(
        NM, FH, H + MF, H,
        molv, mol_feat, nullptr, nullptr, nullptr, nullptr,
        W1, b1, nullptr, nullptr, hbuf);

    // 7. out = relu(hbuf @ W2 + b2)
    gemm_k<0, 2><<<dim3((NM + TM - 1) / TM, EH / TN), blk, 0, stream>>>(
        NM, EH, FH, FH,
        hbuf, nullptr, nullptr, nullptr, nullptr, nullptr,
        W2, b2, nullptr, nullptr, (float*)d_out);
}

// Round 3
// 1112.115 us; speedup vs baseline: 2.5263x; 2.5263x over previous
//
#include <hip/hip_runtime.h>
#include <hip/hip_bf16.h>

// ---------------------------------------------------------------------------
// D-MPNN molecule encoder, round 2: bf16 MFMA for the 4 big GEMMs.
//
//   step1: buf0 = f_bonds @ W_i                (pre-relu, bf16)     [B,256]
//   iter1: amsg = gather-relu-sum(buf0); buf1 = relu(buf0 + diff@W_h)
//   iter2: amsg = gather-relu-sum(buf1); buf0 = relu(buf0 + diff@W_h) in-place
//   final: amsg = gather-relu-sum(buf0)
//   step4: buf1 = relu([f_atoms | amsg] @ W_o_w + b)                [A,256]
//   mean : molv (bsearch over sorted atom2mol)
//   MLP  : fp32 vector GEMMs (M=4096, small)
//
// MFMA GEMM: BM=64 x BN=256(full) x BK=32, 256 thr = 4 waves, each wave a
// 64x64 block via 4x4 of mfma_f32_16x16x32_bf16. A gather/diff/concat fused
// into LDS staging. W pre-transposed to bf16 [N][Kpad32], k-contiguous.
// ---------------------------------------------------------------------------

typedef __hip_bfloat16 bf16;
typedef __attribute__((ext_vector_type(8))) short short8;
typedef __attribute__((ext_vector_type(4))) float f32x4;

__device__ __forceinline__ float b2f(bf16 x) { return __bfloat162float(x); }
__device__ __forceinline__ bf16  f2b(float x) { return __float2bfloat16(x); }
__device__ __forceinline__ float bs2f(short s) {
    unsigned int u = ((unsigned int)(unsigned short)s) << 16;
    float f; __builtin_memcpy(&f, &u, 4); return f;
}
__device__ __forceinline__ short f2bs(float f) {
    bf16 b = __float2bfloat16(f);
    short s; __builtin_memcpy(&s, &b, 2); return s;
}

#define BM 64
#define LDA 40   // LDS row stride in bf16 (80 B -> 2-way bank alias = free)

// A-loader modes
enum { AM_F32 = 0, AM_DIFF = 1, AM_CONCAT = 2 };
// output modes
enum { OM_PRE = 0, OM_RELU = 1 };

// N fixed at 256. Wt: [256][Kp] bf16 k-contiguous, zero-padded to Kp (mult 32).
template <int MODE, int OUT>
__global__ __launch_bounds__(256) void mfma_gemm(
    int M, int K, int Kp, int K1,
    const float* __restrict__ Af,    // AM_F32: [M,K]; AM_CONCAT: [M,K1]
    const bf16* __restrict__ Ab1,    // AM_DIFF: amsg [*,K]; AM_CONCAT: [M,K-K1]
    const bf16* __restrict__ Ab2,    // AM_DIFF: msg [*,K]
    const int* __restrict__ g1,
    const int* __restrict__ g2,
    const bf16* __restrict__ Wt,     // [256][Kp] bf16
    const float* __restrict__ bias,  // [256] or null
    const bf16* __restrict__ addC,   // [M,256] or null (pre-relu residual)
    bf16* __restrict__ out)          // [M,256]
{
    __shared__ bf16 As[BM * LDA];    //  5120 B
    __shared__ bf16 Bs[256 * LDA];   // 20480 B

    const int t    = threadIdx.x;
    const int wave = t >> 6;
    const int lane = t & 63;
    const int bm   = blockIdx.x * BM;

    const int arow   = bm + (t >> 2);   // staging: 4 threads per row
    const int kchunk = (t & 3) * 8;     // this thread's 8-k slice within BK

    int r1 = 0, r2 = 0;
    if (MODE == AM_DIFF && arow < M) { r1 = g1[arow]; r2 = g2[arow]; }

    f32x4 acc[4][4] = {};

    const int mrow = lane & 15;
    const int koff = (lane >> 4) * 8;

    for (int k0 = 0; k0 < K; k0 += 32) {
        // ---- stage A tile: 64 rows x 32 k ----
        {
            short8 av = {};
            int kbase = k0 + kchunk;
            if (arow < M) {
                if (MODE == AM_DIFF) {
                    // K == 256, Kp == K; 16B-aligned fast path, no tail.
                    const short8 x1 = *(const short8*)(Ab1 + (size_t)r1 * K + kbase);
                    const short8 x2 = *(const short8*)(Ab2 + (size_t)r2 * K + kbase);
                    #pragma unroll
                    for (int j = 0; j < 8; j++)
                        av[j] = f2bs(bs2f(x1[j]) - fmaxf(bs2f(x2[j]), 0.f));
                } else if (MODE == AM_F32) {
                    #pragma unroll
                    for (int j = 0; j < 8; j++) {
                        int k = kbase + j;
                        av[j] = (k < K) ? f2bs(Af[(size_t)arow * K + k]) : short(0);
                    }
                } else { // AM_CONCAT
                    #pragma unroll
                    for (int j = 0; j < 8; j++) {
                        int k = kbase + j;
                        float v = 0.f;
                        if (k < K) {
                            v = (k < K1) ? Af[(size_t)arow * K1 + k]
                                         : b2f(Ab1[(size_t)arow * (K - K1) + (k - K1)]);
                        }
                        av[j] = f2bs(v);
                    }
                }
            }
            *(short8*)&As[(t >> 2) * LDA + kchunk] = av;
        }
        // ---- stage B tile: 256 n x 32 k (from Wt, zero-padded, aligned) ----
        #pragma unroll
        for (int g = 0; g < 4; g++) {
            int n = g * 64 + (t >> 2);
            short8 bv = *(const short8*)(Wt + (size_t)n * Kp + k0 + kchunk);
            *(short8*)&Bs[n * LDA + kchunk] = bv;
        }
        __syncthreads();

        // ---- compute: each wave 4x4 of 16x16x32 ----
        short8 afrag[4], bfrag[4];
        #pragma unroll
        for (int tm = 0; tm < 4; tm++)
            afrag[tm] = *(const short8*)&As[(tm * 16 + mrow) * LDA + koff];
        #pragma unroll
        for (int tn = 0; tn < 4; tn++)
            bfrag[tn] = *(const short8*)&Bs[(wave * 64 + tn * 16 + mrow) * LDA + koff];
        #pragma unroll
        for (int tm = 0; tm < 4; tm++)
            #pragma unroll
            for (int tn = 0; tn < 4; tn++)
                acc[tm][tn] = __builtin_amdgcn_mfma_f32_16x16x32_bf16(
                    afrag[tm], bfrag[tn], acc[tm][tn], 0, 0, 0);
        __syncthreads();
    }

    // ---- epilogue: C/D layout col=lane&15, row=(lane>>4)*4+reg ----
    #pragma unroll
    for (int tm = 0; tm < 4; tm++) {
        #pragma unroll
        for (int r = 0; r < 4; r++) {
            int row = bm + tm * 16 + (lane >> 4) * 4 + r;
            if (row >= M) continue;
            #pragma unroll
            for (int tn = 0; tn < 4; tn++) {
                int col = wave * 64 + tn * 16 + (lane & 15);
                float v = acc[tm][tn][r];
                if (bias) v += bias[col];
                size_t o = (size_t)row * 256 + col;
                if (addC) v += b2f(addC[o]);  // same-thread read-before-write when aliased
                if (OUT == OM_RELU) v = fmaxf(v, 0.f);
                out[o] = f2b(v);
            }
        }
    }
}

// W[K][N=256] f32 -> Wt[N][Kp] bf16 (zero pad k in [K,Kp))
__global__ __launch_bounds__(256) void convert_wt(
    const float* __restrict__ W, bf16* __restrict__ Wt, int K, int Kp)
{
    int i = blockIdx.x * 256 + threadIdx.x;
    if (i >= 256 * Kp) return;
    int n = i / Kp, k = i - n * Kp;
    Wt[i] = (k < K) ? f2b(W[(size_t)k * 256 + n]) : f2b(0.f);
}

// amsg[a, c4..c4+4) = sum_k relu(msg[a2b[a,k], c4..c4+4)) ; 8B vector loads
__global__ __launch_bounds__(256) void gather_sum4(
    const bf16* __restrict__ msg, const int* __restrict__ a2b,
    bf16* __restrict__ amsg, int A)
{
    int idx = blockIdx.x * 256 + threadIdx.x;
    if (idx >= A * 64) return;
    int a  = idx >> 6;
    int c4 = (idx & 63) * 4;
    const int* nb = a2b + (size_t)a * 6;
    float s0 = 0.f, s1 = 0.f, s2 = 0.f, s3 = 0.f;
    #pragma unroll
    for (int k = 0; k < 6; k++) {
        typedef __attribute__((ext_vector_type(4))) short short4v;
        const short4v v = *(const short4v*)(msg + (size_t)nb[k] * 256 + c4);
        s0 += fmaxf(bs2f(v[0]), 0.f);
        s1 += fmaxf(bs2f(v[1]), 0.f);
        s2 += fmaxf(bs2f(v[2]), 0.f);
        s3 += fmaxf(bs2f(v[3]), 0.f);
    }
    typedef __attribute__((ext_vector_type(4))) short short4v;
    short4v o; o[0] = f2bs(s0); o[1] = f2bs(s1); o[2] = f2bs(s2); o[3] = f2bs(s3);
    *(short4v*)(amsg + (size_t)a * 256 + c4) = o;
}

// molv[m,h] = mean over the sorted segment atom2mol==m (0 if empty)
__global__ __launch_bounds__(256) void segment_mean_kernel(
    const bf16* __restrict__ ah, const int* __restrict__ atom2mol,
    int A, float* __restrict__ molv)
{
    int m = blockIdx.x;
    int h = threadIdx.x;
    int lo = 0, hi = A;
    while (lo < hi) { int mid = (lo + hi) >> 1; if (atom2mol[mid] < m) lo = mid + 1; else hi = mid; }
    int start = lo;
    hi = A;
    while (lo < hi) { int mid = (lo + hi) >> 1; if (atom2mol[mid] <= m) lo = mid + 1; else hi = mid; }
    int end = lo;
    float s = 0.f;
    for (int a = start; a < end; a++) s += b2f(ah[(size_t)a * 256 + h]);
    float cnt = (float)(end - start);
    molv[(size_t)m * 256 + h] = s / fmaxf(cnt, 1.f);
}

// fp32 vector GEMM for the small MLP: C = relu([A1|A2] @ W + bias)
#define TM 64
#define TN 64
#define TK 16
__global__ __launch_bounds__(256) void gemm_f32(
    int M, int N, int K, int K1,
    const float* __restrict__ Af1,
    const float* __restrict__ Af2,
    const float* __restrict__ W,
    const float* __restrict__ bias,
    float* __restrict__ outF)
{
    __shared__ float As[TK][TM + 4];
    __shared__ float Bs[TK][TN + 4];
    const int bm = blockIdx.x * TM;
    const int bn = blockIdx.y * TN;
    const int t  = threadIdx.x;
    const int tx = t & 15;
    const int ty = t >> 4;
    float acc[4][4] = {};
    for (int k0 = 0; k0 < K; k0 += TK) {
        #pragma unroll
        for (int i = 0; i < 4; i++) {
            int idx = t + i * 256;
            int r = idx >> 4, kk = idx & 15;
            int row = bm + r, k = k0 + kk;
            float v = 0.f;
            if (row < M && k < K)
                v = (k < K1) ? Af1[(size_t)row * K1 + k]
                             : Af2[(size_t)row * (K - K1) + (k - K1)];
            As[kk][r] = v;
        }
        #pragma unroll
        for (int i = 0; i < 4; i++) {
            int idx = t + i * 256;
            int nn = idx & 63, kk = idx >> 6;
            int k = k0 + kk, n = bn + nn;
            float v = 0.f;
            if (k < K && n < N) v = W[(size_t)k * N + n];
            Bs[kk][nn] = v;
        }
        __syncthreads();
        #pragma unroll
        for (int kk = 0; kk < TK; kk++) {
            float a[4], b[4];
            #pragma unroll
            for (int i = 0; i < 4; i++) a[i] = As[kk][ty * 4 + i];
            #pragma unroll
            for (int j = 0; j < 4; j++) b[j] = Bs[kk][tx * 4 + j];
            #pragma unroll
            for (int i = 0; i < 4; i++)
                #pragma unroll
                for (int j = 0; j < 4; j++)
                    acc[i][j] += a[i] * b[j];
        }
        __syncthreads();
    }
    #pragma unroll
    for (int i = 0; i < 4; i++) {
        int row = bm + ty * 4 + i;
        if (row >= M) continue;
        #pragma unroll
        for (int j = 0; j < 4; j++) {
            int n = bn + tx * 4 + j;
            if (n >= N) continue;
            float v = acc[i][j] + (bias ? bias[n] : 0.f);
            outF[(size_t)row * N + n] = fmaxf(v, 0.f);
        }
    }
}

extern "C" void kernel_launch(void* const* d_in, const int* in_sizes, int n_in,
                              void* d_out, int out_size, void* d_ws, size_t ws_size,
                              hipStream_t stream)
{
    const float* f_atoms  = (const float*)d_in[0];
    const float* f_bonds  = (const float*)d_in[1];
    const int*   a2b      = (const int*)d_in[2];
    const int*   b2a      = (const int*)d_in[3];
    const int*   b2revb   = (const int*)d_in[4];
    const int*   atom2mol = (const int*)d_in[5];
    const float* mol_feat = (const float*)d_in[6];
    const float* W_i      = (const float*)d_in[7];
    const float* W_h      = (const float*)d_in[8];
    const float* W_o_w    = (const float*)d_in[9];
    const float* W_o_b    = (const float*)d_in[10];
    const float* W1       = (const float*)d_in[11];
    const float* b1       = (const float*)d_in[12];
    const float* W2       = (const float*)d_in[13];
    const float* b2       = (const float*)d_in[14];

    const int A  = 100000, B = 200000, H = 256;
    const int AF = 133, BF = 147;
    const int NM = 4096, MF = 200, FH = 512, EH = 256;
    const int KpI = 160, KpH = 256, KpO = 416;   // K padded to mult of 32

    char* ws = (char*)d_ws;
    bf16* buf0 = (bf16*)ws;  ws += (size_t)B * H * sizeof(bf16);     // 102.4 MB
    bf16* buf1 = (bf16*)ws;  ws += (size_t)B * H * sizeof(bf16);     // 102.4 MB
    bf16* amsg = (bf16*)ws;  ws += (size_t)A * H * sizeof(bf16);     //  51.2 MB
    float* molv = (float*)ws; ws += (size_t)NM * H * sizeof(float);  //   4 MB
    float* hbuf = (float*)ws; ws += (size_t)NM * FH * sizeof(float); //   8 MB
    bf16* WtI = (bf16*)ws;   ws += (size_t)256 * KpI * sizeof(bf16);
    bf16* WtH = (bf16*)ws;   ws += (size_t)256 * KpH * sizeof(bf16);
    bf16* WtO = (bf16*)ws;   ws += (size_t)256 * KpO * sizeof(bf16);

    dim3 blk(256);
    const int gsB = (B + BM - 1) / BM;      // 3125
    const int gsA = (A + BM - 1) / BM;      // 1563
    const int gsG = (A * 64 + 255) / 256;   // 25000

    // 0. pre-transpose/convert weights to bf16 [N][Kp]
    convert_wt<<<dim3((256 * KpI + 255) / 256), blk, 0, stream>>>(W_i, WtI, BF, KpI);
    convert_wt<<<dim3((256 * KpH + 255) / 256), blk, 0, stream>>>(W_h, WtH, H, KpH);
    convert_wt<<<dim3((256 * KpO + 255) / 256), blk, 0, stream>>>(W_o_w, WtO, AF + H, KpO);

    // 1. buf0 = f_bonds @ W_i  (pre-relu)
    mfma_gemm<AM_F32, OM_PRE><<<dim3(gsB), blk, 0, stream>>>(
        B, BF, KpI, BF, f_bonds, nullptr, nullptr, nullptr, nullptr,
        WtI, nullptr, nullptr, buf0);

    // 2a. iter 1 (rev-gather source buf0; relu-on-read makes it msg0)
    gather_sum4<<<dim3(gsG), blk, 0, stream>>>(buf0, a2b, amsg, A);
    mfma_gemm<AM_DIFF, OM_RELU><<<dim3(gsB), blk, 0, stream>>>(
        B, H, KpH, H, nullptr, amsg, buf0, b2a, b2revb,
        WtH, nullptr, buf0, buf1);

    // 2b. iter 2 (in-place into buf0; residual read same-thread pre-write)
    gather_sum4<<<dim3(gsG), blk, 0, stream>>>(buf1, a2b, amsg, A);
    mfma_gemm<AM_DIFF, OM_RELU><<<dim3(gsB), blk, 0, stream>>>(
        B, H, KpH, H, nullptr, amsg, buf1, b2a, b2revb,
        WtH, nullptr, buf0, buf0);

    // 3. final neighbor sum (relu-on-read idempotent)
    gather_sum4<<<dim3(gsG), blk, 0, stream>>>(buf0, a2b, amsg, A);

    // 4. buf1 = relu([f_atoms | amsg] @ W_o_w + b)
    mfma_gemm<AM_CONCAT, OM_RELU><<<dim3(gsA), blk, 0, stream>>>(
        A, AF + H, KpO, AF, f_atoms, amsg, nullptr, nullptr, nullptr,
        WtO, W_o_b, nullptr, buf1);

    // 5. per-molecule mean
    segment_mean_kernel<<<dim3(NM), blk, 0, stream>>>(buf1, atom2mol, A, molv);

    // 6. hbuf = relu([molv | mol_feat] @ W1 + b1)
    gemm_f32<<<dim3((NM + TM - 1) / TM, FH / TN), blk, 0, stream>>>(
        NM, FH, H + MF, H, molv, mol_feat, W1, b1, hbuf);

    // 7. out = relu(hbuf @ W2 + b2)
    gemm_f32<<<dim3((NM + TM - 1) / TM, EH / TN), blk, 0, stream>>>(
        NM, EH, FH, FH, hbuf, nullptr, W2, b2, (float*)d_out);
}